// Round 7
// baseline (275.237 us; speedup 1.0000x reference)
//
#include <hip/hip_runtime.h>

#define BB 2
#define SS 2048
#define DD 1024
#define HH 16
#define WW 64
#define MM (BB*SS)  // 4096

typedef float f32x4 __attribute__((ext_vector_type(4)));
typedef short s16x8 __attribute__((ext_vector_type(8)));

__device__ __forceinline__ unsigned short f2bf(float f) {
  return __builtin_bit_cast(unsigned short, (__bf16)f);
}
__device__ __forceinline__ float bf2f(unsigned short u) {
  return (float)__builtin_bit_cast(__bf16, u);
}
// async global->LDS DMA, 16B per lane; lds dst must be wave-uniform (HW adds lane*16)
__device__ __forceinline__ void dma16(const unsigned short* g, unsigned short* l) {
  __builtin_amdgcn_global_load_lds(
      (const __attribute__((address_space(1))) unsigned int*)g,
      (__attribute__((address_space(3))) unsigned int*)l, 16, 0, 0);
}

// ---------------- pre-pass: x fp32 -> bf16 ----------------
__global__ __launch_bounds__(256) void k_convert_x(const float* __restrict__ x,
                                                   unsigned short* __restrict__ xb) {
  int i = (blockIdx.x * 256 + threadIdx.x) * 4;
  float4 v = *(const float4*)(x + i);
  ushort4 o = make_ushort4(f2bf(v.x), f2bf(v.y), f2bf(v.z), f2bf(v.w));
  *(ushort4*)(xb + i) = o;
}

// ---------------- pre-pass: W (KxN fp32) -> Wt (NxK bf16) ----------------
__global__ __launch_bounds__(256) void k_transpose_w(const float* __restrict__ Wm,
                                                     unsigned short* __restrict__ Wt) {
  __shared__ float tile[32][33];
  int bn = blockIdx.x * 32;
  int bk = blockIdx.y * 32;
  int tx = threadIdx.x;
  int ty = threadIdx.y;
#pragma unroll
  for (int r = 0; r < 4; ++r)
    tile[ty + r * 8][tx] = Wm[(bk + ty + r * 8) * DD + bn + tx];
  __syncthreads();
#pragma unroll
  for (int r = 0; r < 4; ++r)
    Wt[(bn + ty + r * 8) * DD + bk + tx] = f2bf(tile[tx][ty + r * 8]);
}

// ---------------- bf16 MFMA GEMM: C = A(M,K) * Bt(N,K)^T + bias ----------------
// m97-style 128x128 tile, BK=32, global_load_lds width-16 staging into
// DOUBLE-BUFFERED XOR-swizzled LDS (phys 16B-block = logical ^ (row&3)).
// Grid is only 256 blocks (1/CU) so the explicit dbuf pipeline
// (vmcnt(0) -> barrier -> DMA(next) -> compute) is what hides the DMA drain.
// Each wave computes a 64x64 quadrant: 4x4 f32x4 acc, 16 MFMA + 8 ds_read_b128
// + 4 dma16 per BK-iter.
// modes: 0 = bf16 head-layout scaled (Q); 1 = bf16 per-head transposed (V^T);
//        2 = bf16 head-layout (K); 3 = fp32 row-major (final output)
__global__ __launch_bounds__(256) void k_gemm(const unsigned short* __restrict__ A,
                                              const unsigned short* __restrict__ Bt,
                                              const float* __restrict__ bias,
                                              unsigned short* __restrict__ out_bf,
                                              float* __restrict__ out_f,
                                              int mode, float oscale) {
  __shared__ __align__(16) unsigned short As[2][128 * 32];  // 8 KB each
  __shared__ __align__(16) unsigned short Bs[2][128 * 32];
  const int m0 = blockIdx.y * 128, n0 = blockIdx.x * 128;
  const int t = threadIdx.x;
  const int wv = t >> 6, lane = t & 63;
  const int quad = lane >> 4, l16 = lane & 15;
  const int wm = (wv >> 1) * 64, wn = (wv & 1) * 64;
  // DMA mapping: slot s (0..511) = 16B block; wave wv + issue d covers
  // slots d*256 + wv*64 + lane. r = s>>2, phys block pb = s&3 holds logical
  // block pb ^ (r&3) -> source col = ((pb^(r&3))*8 elems.
  const unsigned short* srcA[2];
  const unsigned short* srcB[2];
  int dstoff[2];
#pragma unroll
  for (int d = 0; d < 2; ++d) {
    int s = d * 256 + wv * 64 + lane;
    int r = s >> 2, pb = s & 3;
    int lc = ((pb ^ (r & 3)) << 3);
    srcA[d] = A + (size_t)(m0 + r) * DD + lc;
    srcB[d] = Bt + (size_t)(n0 + r) * DD + lc;
    dstoff[d] = (d * 256 + wv * 64) * 8;  // elems; wave-uniform
  }
  f32x4 acc[4][4] = {};

  // prologue: stage k0=0 into buffer 0
#pragma unroll
  for (int d = 0; d < 2; ++d) {
    dma16(srcA[d], &As[0][dstoff[d]]);
    dma16(srcB[d], &Bs[0][dstoff[d]]);
  }

  for (int it = 0; it < DD / 32; ++it) {
    asm volatile("s_waitcnt vmcnt(0)" ::: "memory");  // this buffer's DMA landed
    __syncthreads();                                  // all waves' DMA visible; prev reads done
    if (it + 1 < DD / 32) {
      const int nb = (it + 1) & 1;
      const int k1 = (it + 1) * 32;
#pragma unroll
      for (int d = 0; d < 2; ++d) {
        dma16(srcA[d] + k1, &As[nb][dstoff[d]]);
        dma16(srcB[d] + k1, &Bs[nb][dstoff[d]]);
      }
    }
    const unsigned short* Asb = As[it & 1];
    const unsigned short* Bsb = Bs[it & 1];
    s16x8 af[4], bfr[4];
#pragma unroll
    for (int mi = 0; mi < 4; ++mi) {
      int ra = wm + mi * 16 + l16;
      af[mi] = *(const s16x8*)(Asb + ra * 32 + ((quad ^ (ra & 3)) << 3));
    }
#pragma unroll
    for (int ni = 0; ni < 4; ++ni) {
      int rb = wn + ni * 16 + l16;
      bfr[ni] = *(const s16x8*)(Bsb + rb * 32 + ((quad ^ (rb & 3)) << 3));
    }
#pragma unroll
    for (int mi = 0; mi < 4; ++mi)
#pragma unroll
      for (int ni = 0; ni < 4; ++ni)
        acc[mi][ni] = __builtin_amdgcn_mfma_f32_16x16x32_bf16(af[mi], bfr[ni], acc[mi][ni], 0, 0, 0);
  }

#pragma unroll
  for (int mi = 0; mi < 4; ++mi) {
#pragma unroll
    for (int ni = 0; ni < 4; ++ni) {
      int col = n0 + wn + ni * 16 + l16;
      float bb = bias[col];
#pragma unroll
      for (int r = 0; r < 4; ++r) {
        int row = m0 + wm + mi * 16 + quad * 4 + r;  // C/D: row = quad*4 + reg
        float v = (acc[mi][ni][r] + bb) * oscale;
        if (mode == 3) {
          out_f[row * DD + col] = v;
        } else {
          int b = row >> 11, s = row & (SS - 1);
          int h = col >> 6, w = col & 63;
          long off;
          if (mode == 1) off = (long)(b * HH + h) * (SS * WW) + (long)w * SS + s;
          else           off = (long)(b * HH + h) * (SS * WW) + (long)s * WW + w;
          out_bf[off] = f2bf(v);
        }
      }
    }
  }
}

// ---------------- MFMA flash attention: LDS-staged, DMA dbuf, PAIRED strips ----------------
// Block = 256 threads = 4 waves. Block p (p=0..7) processes TWO 128-query
// strips sequentially: strip p then strip 15-p -> every block does exactly
// (2p+2)+(32-2p) = 34 k-tiles: perfect load balance, no tail.
// Per strip: R6 pipeline (K/V 64-key tiles DMA'd into double-buffered
// XOR-swizzled LDS; vmcnt(0) -> barrier -> DMA(kt+1) -> compute(kt)).
__global__ __launch_bounds__(256, 2) void k_attn_mfma(const unsigned short* __restrict__ Q,
                                                      const unsigned short* __restrict__ K,
                                                      const unsigned short* __restrict__ Vt,
                                                      unsigned short* __restrict__ hm) {
  constexpr int LDP = 72;
  __shared__ __align__(16) unsigned short Kbuf[2][64 * 64];  // 16 KB
  __shared__ __align__(16) unsigned short Vbuf[2][64 * 64];  // 16 KB
  __shared__ __align__(16) unsigned short Pl4[4][32 * LDP];  // 18.4 KB
  const int pairp = blockIdx.x;  // 0..7
  const int bh = blockIdx.y;
  const int t = threadIdx.x;
  const int wv = t >> 6, lane = t & 63;
  const int quad = lane >> 4, l16 = lane & 15;
  unsigned short* Pl = Pl4[wv];
  const unsigned short* Qp = Q + (size_t)bh * SS * WW;
  const unsigned short* Kp = K + (size_t)bh * SS * WW;
  const unsigned short* Vp = Vt + (size_t)bh * WW * SS;
  const int b = bh >> 4, h = bh & 15;

  // staging geometry: lane = 8*rr + cc; DMA d covers rows wv*16 + d*8 .. +7
  const int rr = lane >> 3, cc = lane & 7;
  const int srow = wv * 16 + rr;
  const int scol = ((cc ^ (rr & 7)) << 3);  // swizzled logical col (elems)

  for (int sp = 0; sp < 2; ++sp) {
    const int strip = sp == 0 ? pairp : 15 - pairp;
    const int qs = strip * 128;
    const int qb = qs + wv * 32;
    const int q_hi = qb + 31;

    // Q B-fragments: B[n=q_local=l16][k=dim=quad*8+j]
    s16x8 qf[2][2];
#pragma unroll
    for (int nt = 0; nt < 2; ++nt)
#pragma unroll
      for (int c = 0; c < 2; ++c)
        qf[nt][c] = *(const s16x8*)(Qp + (qb + nt * 16 + l16) * WW + c * 32 + quad * 8);

    f32x4 O[2][4] = {};  // C/D: row=q=quad*4+r (+16*mi), col=dim=l16 (+16*ni)
    float m[2], l[2];
    m[0] = m[1] = -__builtin_inff();
    l[0] = l[1] = 0.f;

    const int nkt = qs / 64 + 2;  // tiles needed by wave 3

    // prologue: stage tile 0 into buffer 0
#pragma unroll
    for (int d = 0; d < 2; ++d) {
      dma16(Kp + (size_t)(srow + d * 8) * WW + scol, &Kbuf[0][(wv * 16 + d * 8) * 64]);
      dma16(Vp + (size_t)(srow + d * 8) * SS + scol, &Vbuf[0][(wv * 16 + d * 8) * 64]);
    }

    for (int kt = 0; kt < nkt; ++kt) {
      const int kb = kt * 64;
      asm volatile("s_waitcnt vmcnt(0)" ::: "memory");  // this tile's DMA landed
      __syncthreads();                                  // all waves' DMA visible; prev compute done
      if (kt + 1 < nkt) {                               // prefetch next tile
        const int nb = (kt + 1) & 1;
        const int kbn = kb + 64;
#pragma unroll
        for (int d = 0; d < 2; ++d) {
          dma16(Kp + (size_t)(kbn + srow + d * 8) * WW + scol, &Kbuf[nb][(wv * 16 + d * 8) * 64]);
          dma16(Vp + (size_t)(srow + d * 8) * SS + kbn + scol, &Vbuf[nb][(wv * 16 + d * 8) * 64]);
        }
      }
      if (kb > q_hi) continue;  // wave-uniform; still hits barriers for staging
      const unsigned short* Kb_ = Kbuf[kt & 1];
      const unsigned short* Vb_ = Vbuf[kt & 1];

      // K A-fragments from LDS: logical block c*4+quad, phys = lb^(row&7)
      s16x8 kf[4][2];
#pragma unroll
      for (int mt = 0; mt < 4; ++mt)
#pragma unroll
        for (int c = 0; c < 2; ++c)
          kf[mt][c] = *(const s16x8*)(Kb_ + (mt * 16 + l16) * 64 + (((c * 4 + quad) ^ (l16 & 7)) << 3));

      // S^T tiles: row=key_local=quad*4+r (+16*mt), col=q_local=l16 (+16*nt)
      f32x4 sc[4][2] = {};
#pragma unroll
      for (int mt = 0; mt < 4; ++mt)
#pragma unroll
        for (int nt = 0; nt < 2; ++nt)
#pragma unroll
          for (int c = 0; c < 2; ++c)
            sc[mt][nt] = __builtin_amdgcn_mfma_f32_16x16x32_bf16(kf[mt][c], qf[nt][c], sc[mt][nt], 0, 0, 0);

      if (kb + 63 > qb) {  // diagonal-overlapping tile: causal mask
#pragma unroll
        for (int mt = 0; mt < 4; ++mt)
#pragma unroll
          for (int nt = 0; nt < 2; ++nt)
#pragma unroll
            for (int r = 0; r < 4; ++r)
              if (kb + mt * 16 + quad * 4 + r > qb + nt * 16 + l16)
                sc[mt][nt][r] = -__builtin_inff();
      }

      // online softmax (exp2 domain); stats per q = nt*16 + l16
      float alpha[2];
#pragma unroll
      for (int nt = 0; nt < 2; ++nt) {
        float mx = sc[0][nt][0];
#pragma unroll
        for (int mt = 0; mt < 4; ++mt)
#pragma unroll
          for (int r = 0; r < 4; ++r) mx = fmaxf(mx, sc[mt][nt][r]);
        mx = fmaxf(mx, __shfl_xor(mx, 16));
        mx = fmaxf(mx, __shfl_xor(mx, 32));
        float mn = fmaxf(m[nt], mx);
        alpha[nt] = __builtin_amdgcn_exp2f(m[nt] - mn);
        float s = 0.f;
#pragma unroll
        for (int mt = 0; mt < 4; ++mt)
#pragma unroll
          for (int r = 0; r < 4; ++r) {
            float p = __builtin_amdgcn_exp2f(sc[mt][nt][r] - mn);
            sc[mt][nt][r] = p;
            s += p;
          }
        s += __shfl_xor(s, 16);
        s += __shfl_xor(s, 32);
        l[nt] = l[nt] * alpha[nt] + s;
        m[nt] = mn;
      }

      // rescale O: rows q = mi*16 + quad*4 + r -> alpha from lane (quad*4+r)
#pragma unroll
      for (int mi = 0; mi < 2; ++mi)
#pragma unroll
        for (int r = 0; r < 4; ++r) {
          float aT = __shfl(alpha[mi], quad * 4 + r);
#pragma unroll
          for (int ni = 0; ni < 4; ++ni) O[mi][ni][r] *= aT;
        }

      // P -> per-wave LDS region (layout transform C/D -> A-operand)
      asm volatile("s_waitcnt lgkmcnt(0)" ::: "memory");  // WAR: prev pf reads done
#pragma unroll
      for (int mt = 0; mt < 4; ++mt)
#pragma unroll
        for (int nt = 0; nt < 2; ++nt) {
          ushort4 pw = make_ushort4(f2bf(sc[mt][nt][0]), f2bf(sc[mt][nt][1]),
                                    f2bf(sc[mt][nt][2]), f2bf(sc[mt][nt][3]));
          *(ushort4*)(Pl + (nt * 16 + l16) * LDP + mt * 16 + quad * 4) = pw;
        }
      asm volatile("s_waitcnt lgkmcnt(0)" ::: "memory");  // RAW: stores visible

      // V^T B-fragments from LDS (kf dead by now)
      s16x8 vf[4][2];
#pragma unroll
      for (int ni = 0; ni < 4; ++ni)
#pragma unroll
        for (int c = 0; c < 2; ++c)
          vf[ni][c] = *(const s16x8*)(Vb_ + (ni * 16 + l16) * 64 + (((c * 4 + quad) ^ (l16 & 7)) << 3));

      // P A-fragments
      s16x8 pf[2][2];
#pragma unroll
      for (int mi = 0; mi < 2; ++mi)
#pragma unroll
        for (int c = 0; c < 2; ++c)
          pf[mi][c] = *(const s16x8*)(Pl + (mi * 16 + l16) * LDP + c * 32 + quad * 8);

      // O += P * V^T
#pragma unroll
      for (int mi = 0; mi < 2; ++mi)
#pragma unroll
        for (int ni = 0; ni < 4; ++ni)
#pragma unroll
          for (int c = 0; c < 2; ++c)
            O[mi][ni] = __builtin_amdgcn_mfma_f32_16x16x32_bf16(pf[mi][c], vf[ni][c], O[mi][ni], 0, 0, 0);
    }

    // epilogue: divide by l, write head-merged (B,S,D)
#pragma unroll
    for (int mi = 0; mi < 2; ++mi)
#pragma unroll
      for (int r = 0; r < 4; ++r) {
        float linv = 1.f / __shfl(l[mi], quad * 4 + r);
        int q = qb + mi * 16 + quad * 4 + r;
#pragma unroll
        for (int ni = 0; ni < 4; ++ni)
          hm[(size_t)(b * SS + q) * DD + h * WW + ni * 16 + l16] = f2bf(O[mi][ni][r] * linv);
      }
    __syncthreads();  // all waves done with Kbuf/Vbuf before next strip's prologue DMA
  }
}

extern "C" void kernel_launch(void* const* d_in, const int* in_sizes, int n_in,
                              void* d_out, int out_size, void* d_ws, size_t ws_size,
                              hipStream_t stream) {
  const float* x  = (const float*)d_in[0];
  // d_in[1] = seg : unused by the reference
  const float* Wq = (const float*)d_in[2];
  const float* bq = (const float*)d_in[3];
  const float* Wk = (const float*)d_in[4];
  const float* bk = (const float*)d_in[5];
  const float* Wv = (const float*)d_in[6];
  const float* bv = (const float*)d_in[7];
  const float* Wo = (const float*)d_in[8];
  const float* bo = (const float*)d_in[9];
  float* out = (float*)d_out;

  char* ws = (char*)d_ws;
  unsigned short* xb  = (unsigned short*)(ws);                      // 8 MB
  unsigned short* Wtq = (unsigned short*)(ws + (size_t)( 8 << 20)); // 2 MB each
  unsigned short* Wtk = (unsigned short*)(ws + (size_t)(10 << 20));
  unsigned short* Wtv = (unsigned short*)(ws + (size_t)(12 << 20));
  unsigned short* Wto = (unsigned short*)(ws + (size_t)(14 << 20));
  unsigned short* Qb  = (unsigned short*)(ws + (size_t)(16 << 20)); // 8 MB (B,H,S,W)
  unsigned short* Kb  = (unsigned short*)(ws + (size_t)(24 << 20)); // 8 MB (B,H,S,W)
  unsigned short* Vtb = (unsigned short*)(ws + (size_t)(32 << 20)); // 8 MB (B,H,W,S)
  unsigned short* hm  = (unsigned short*)(ws + (size_t)(40 << 20)); // 8 MB (B,S,D)

  k_convert_x<<<dim3(MM * DD / 1024), 256, 0, stream>>>(x, xb);

  dim3 tg(32, 32), tb(32, 8);
  k_transpose_w<<<tg, tb, 0, stream>>>(Wq, Wtq);
  k_transpose_w<<<tg, tb, 0, stream>>>(Wk, Wtk);
  k_transpose_w<<<tg, tb, 0, stream>>>(Wv, Wtv);
  k_transpose_w<<<tg, tb, 0, stream>>>(Wo, Wto);

  dim3 gg(DD / 128, MM / 128);  // (8, 32) = 256 blocks
  // Q pre-scaled by log2(e)/sqrt(64) so softmax runs in exp2 domain
  k_gemm<<<gg, 256, 0, stream>>>(xb, Wtq, bq, Qb, nullptr, 0, 0.125f * 1.4426950408889634f);
  k_gemm<<<gg, 256, 0, stream>>>(xb, Wtk, bk, Kb, nullptr, 2, 1.0f);    // K head-layout
  k_gemm<<<gg, 256, 0, stream>>>(xb, Wtv, bv, Vtb, nullptr, 1, 1.0f);   // V^T per head
  dim3 ag(SS / 256, BB * HH);  // (8, 32): block p does strips p and 15-p
  k_attn_mfma<<<ag, 256, 0, stream>>>(Qb, Kb, Vtb, hm);

  k_gemm<<<gg, 256, 0, stream>>>(hm, Wto, bo, nullptr, out, 3, 1.0f);   // final projection, fp32
}

// Round 8
// 220.529 us; speedup vs baseline: 1.2481x; 1.2481x over previous
//
#include <hip/hip_runtime.h>

#define BB 2
#define SS 2048
#define DD 1024
#define HH 16
#define WW 64
#define MM (BB*SS)  // 4096

typedef float f32x4 __attribute__((ext_vector_type(4)));
typedef short s16x8 __attribute__((ext_vector_type(8)));

__device__ __forceinline__ unsigned short f2bf(float f) {
  return __builtin_bit_cast(unsigned short, (__bf16)f);
}
__device__ __forceinline__ float bf2f(unsigned short u) {
  return (float)__builtin_bit_cast(__bf16, u);
}
// async global->LDS DMA, 16B per lane; lds dst must be wave-uniform (HW adds lane*16)
__device__ __forceinline__ void dma16(const unsigned short* g, unsigned short* l) {
  __builtin_amdgcn_global_load_lds(
      (const __attribute__((address_space(1))) unsigned int*)g,
      (__attribute__((address_space(3))) unsigned int*)l, 16, 0, 0);
}

// ---------------- pre-pass: x fp32 -> bf16 ----------------
__global__ __launch_bounds__(256) void k_convert_x(const float* __restrict__ x,
                                                   unsigned short* __restrict__ xb) {
  int i = (blockIdx.x * 256 + threadIdx.x) * 4;
  float4 v = *(const float4*)(x + i);
  ushort4 o = make_ushort4(f2bf(v.x), f2bf(v.y), f2bf(v.z), f2bf(v.w));
  *(ushort4*)(xb + i) = o;
}

// ---------------- pre-pass: 4x W (KxN fp32) -> Wt (NxK bf16), fused ----------------
__global__ __launch_bounds__(256) void k_transpose_w(const float* __restrict__ W0,
                                                     const float* __restrict__ W1,
                                                     const float* __restrict__ W2,
                                                     const float* __restrict__ W3,
                                                     unsigned short* __restrict__ T0,
                                                     unsigned short* __restrict__ T1,
                                                     unsigned short* __restrict__ T2,
                                                     unsigned short* __restrict__ T3) {
  const float* Wm = blockIdx.z == 0 ? W0 : blockIdx.z == 1 ? W1 : blockIdx.z == 2 ? W2 : W3;
  unsigned short* Wt = blockIdx.z == 0 ? T0 : blockIdx.z == 1 ? T1 : blockIdx.z == 2 ? T2 : T3;
  __shared__ float tile[32][33];
  int bn = blockIdx.x * 32;
  int bk = blockIdx.y * 32;
  int tx = threadIdx.x;
  int ty = threadIdx.y;
#pragma unroll
  for (int r = 0; r < 4; ++r)
    tile[ty + r * 8][tx] = Wm[(bk + ty + r * 8) * DD + bn + tx];
  __syncthreads();
#pragma unroll
  for (int r = 0; r < 4; ++r)
    Wt[(bn + ty + r * 8) * DD + bk + tx] = f2bf(tile[tx][ty + r * 8]);
}

// ---------------- fused QKV GEMM: [Q|K|V] = x * [Wtq|Wtk|Wtv]^T + bias ----------------
// 128x128 tile, BK=32, global_load_lds width-16 into double-buffered
// XOR-swizzled LDS (phys 16B-block = logical ^ (row&3)). Grid (24,32) = 768
// blocks = 3 blocks/CU: the m97 occupancy regime (implicit TLP hides the
// vmcnt/barrier drain). widx = bx>>3 selects weight/output/epilogue:
//   0 -> Q bf16 head-layout (B,H,S,W), scaled by log2(e)/8
//   1 -> K bf16 head-layout
//   2 -> V^T bf16 per-head transposed (B,H,W,S)
__global__ __launch_bounds__(256, 3) void k_gemm_qkv(const unsigned short* __restrict__ A,
                                                     const unsigned short* __restrict__ Wcat,
                                                     const float* __restrict__ bq,
                                                     const float* __restrict__ bk,
                                                     const float* __restrict__ bv,
                                                     unsigned short* __restrict__ Qo,
                                                     unsigned short* __restrict__ Ko,
                                                     unsigned short* __restrict__ Vo) {
  __shared__ __align__(16) unsigned short As[2][128 * 32];  // 8 KB each
  __shared__ __align__(16) unsigned short Bs[2][128 * 32];
  const int widx = blockIdx.x >> 3;
  const int n0 = (blockIdx.x & 7) * 128;
  const int m0 = blockIdx.y * 128;
  const unsigned short* Bt = Wcat + (size_t)widx * DD * DD;
  const float* bias = widx == 0 ? bq : widx == 1 ? bk : bv;
  unsigned short* outp = widx == 0 ? Qo : widx == 1 ? Ko : Vo;
  const float oscale = widx == 0 ? 0.125f * 1.4426950408889634f : 1.0f;
  const int t = threadIdx.x;
  const int wv = t >> 6, lane = t & 63;
  const int quad = lane >> 4, l16 = lane & 15;
  const int wm = (wv >> 1) * 64, wn = (wv & 1) * 64;
  // DMA mapping: slot s (0..511) = 16B block; r = s>>2, phys block pb = s&3
  // holds logical block pb^(r&3) -> source col = (pb^(r&3))*8 elems.
  const unsigned short* srcA[2];
  const unsigned short* srcB[2];
  int dstoff[2];
#pragma unroll
  for (int d = 0; d < 2; ++d) {
    int s = d * 256 + wv * 64 + lane;
    int r = s >> 2, pb = s & 3;
    int lc = ((pb ^ (r & 3)) << 3);
    srcA[d] = A + (size_t)(m0 + r) * DD + lc;
    srcB[d] = Bt + (size_t)(n0 + r) * DD + lc;
    dstoff[d] = (d * 256 + wv * 64) * 8;  // elems; wave-uniform
  }
  f32x4 acc[4][4] = {};

#pragma unroll
  for (int d = 0; d < 2; ++d) {
    dma16(srcA[d], &As[0][dstoff[d]]);
    dma16(srcB[d], &Bs[0][dstoff[d]]);
  }

  for (int it = 0; it < DD / 32; ++it) {
    asm volatile("s_waitcnt vmcnt(0)" ::: "memory");
    __syncthreads();
    if (it + 1 < DD / 32) {
      const int nb = (it + 1) & 1;
      const int k1 = (it + 1) * 32;
#pragma unroll
      for (int d = 0; d < 2; ++d) {
        dma16(srcA[d] + k1, &As[nb][dstoff[d]]);
        dma16(srcB[d] + k1, &Bs[nb][dstoff[d]]);
      }
    }
    const unsigned short* Asb = As[it & 1];
    const unsigned short* Bsb = Bs[it & 1];
    s16x8 af[4], bfr[4];
#pragma unroll
    for (int mi = 0; mi < 4; ++mi) {
      int ra = wm + mi * 16 + l16;
      af[mi] = *(const s16x8*)(Asb + ra * 32 + ((quad ^ (ra & 3)) << 3));
    }
#pragma unroll
    for (int ni = 0; ni < 4; ++ni) {
      int rb = wn + ni * 16 + l16;
      bfr[ni] = *(const s16x8*)(Bsb + rb * 32 + ((quad ^ (rb & 3)) << 3));
    }
#pragma unroll
    for (int mi = 0; mi < 4; ++mi)
#pragma unroll
      for (int ni = 0; ni < 4; ++ni)
        acc[mi][ni] = __builtin_amdgcn_mfma_f32_16x16x32_bf16(af[mi], bfr[ni], acc[mi][ni], 0, 0, 0);
  }

#pragma unroll
  for (int mi = 0; mi < 4; ++mi) {
#pragma unroll
    for (int ni = 0; ni < 4; ++ni) {
      int col = n0 + wn + ni * 16 + l16;
      float bb = bias[col];
      int h = col >> 6, w = col & 63;
#pragma unroll
      for (int r = 0; r < 4; ++r) {
        int row = m0 + wm + mi * 16 + quad * 4 + r;  // C/D: row = quad*4 + reg
        float v = (acc[mi][ni][r] + bb) * oscale;
        int b = row >> 11, s = row & (SS - 1);
        long off;
        if (widx == 2) off = (long)(b * HH + h) * (SS * WW) + (long)w * SS + s;
        else           off = (long)(b * HH + h) * (SS * WW) + (long)s * WW + w;
        outp[off] = f2bf(v);
      }
    }
  }
}

// ---------------- output GEMM: out = hm * Wto^T + bo (fp32) ----------------
// R1-proven 64x64 tile, BK=32, register-staged LDS (LDK=40 pad), grid
// (16,64) = 1024 blocks = 4 blocks/CU.
__global__ __launch_bounds__(256) void k_gemm_out(const unsigned short* __restrict__ A,
                                                  const unsigned short* __restrict__ Bt,
                                                  const float* __restrict__ bias,
                                                  float* __restrict__ out_f) {
  constexpr int LDK = 40;
  __shared__ __align__(16) unsigned short As[64 * LDK];
  __shared__ __align__(16) unsigned short Bs[64 * LDK];
  const int m0 = blockIdx.y * 64, n0 = blockIdx.x * 64;
  const int t = threadIdx.x;
  const int wv = t >> 6, lane = t & 63;
  const int quad = lane >> 4, l16 = lane & 15;
  const int sr = t >> 2, sk = (t & 3) * 8;
  const int wm = (wv >> 1) * 32, wn = (wv & 1) * 32;
  f32x4 acc[2][2] = {};

  for (int k0 = 0; k0 < DD; k0 += 32) {
    uint4 av = *(const uint4*)(A + (m0 + sr) * DD + k0 + sk);
    uint4 bv = *(const uint4*)(Bt + (n0 + sr) * DD + k0 + sk);
    __syncthreads();
    *(uint4*)(As + sr * LDK + sk) = av;
    *(uint4*)(Bs + sr * LDK + sk) = bv;
    __syncthreads();
    s16x8 af[2], bfr[2];
#pragma unroll
    for (int i = 0; i < 2; ++i) {
      af[i]  = *(const s16x8*)(As + (wm + i * 16 + l16) * LDK + quad * 8);
      bfr[i] = *(const s16x8*)(Bs + (wn + i * 16 + l16) * LDK + quad * 8);
    }
#pragma unroll
    for (int mi = 0; mi < 2; ++mi)
#pragma unroll
      for (int ni = 0; ni < 2; ++ni)
        acc[mi][ni] = __builtin_amdgcn_mfma_f32_16x16x32_bf16(af[mi], bfr[ni], acc[mi][ni], 0, 0, 0);
  }

#pragma unroll
  for (int mi = 0; mi < 2; ++mi)
#pragma unroll
    for (int ni = 0; ni < 2; ++ni) {
      int col = n0 + wn + ni * 16 + l16;
      float bb = bias[col];
#pragma unroll
      for (int r = 0; r < 4; ++r) {
        int row = m0 + wm + mi * 16 + quad * 4 + r;
        out_f[row * DD + col] = acc[mi][ni][r] + bb;
      }
    }
}

// ---------------- MFMA flash attention: LDS-staged, DMA dbuf, PAIRED strips ----------------
// (unchanged from R7: 71.6 us measured) Block p processes strips p and 15-p
// sequentially -> exactly 34 k-tiles per block.
__global__ __launch_bounds__(256, 2) void k_attn_mfma(const unsigned short* __restrict__ Q,
                                                      const unsigned short* __restrict__ K,
                                                      const unsigned short* __restrict__ Vt,
                                                      unsigned short* __restrict__ hm) {
  constexpr int LDP = 72;
  __shared__ __align__(16) unsigned short Kbuf[2][64 * 64];
  __shared__ __align__(16) unsigned short Vbuf[2][64 * 64];
  __shared__ __align__(16) unsigned short Pl4[4][32 * LDP];
  const int pairp = blockIdx.x;  // 0..7
  const int bh = blockIdx.y;
  const int t = threadIdx.x;
  const int wv = t >> 6, lane = t & 63;
  const int quad = lane >> 4, l16 = lane & 15;
  unsigned short* Pl = Pl4[wv];
  const unsigned short* Qp = Q + (size_t)bh * SS * WW;
  const unsigned short* Kp = K + (size_t)bh * SS * WW;
  const unsigned short* Vp = Vt + (size_t)bh * WW * SS;
  const int b = bh >> 4, h = bh & 15;

  const int rr = lane >> 3, cc = lane & 7;
  const int srow = wv * 16 + rr;
  const int scol = ((cc ^ (rr & 7)) << 3);

  for (int sp = 0; sp < 2; ++sp) {
    const int strip = sp == 0 ? pairp : 15 - pairp;
    const int qs = strip * 128;
    const int qb = qs + wv * 32;
    const int q_hi = qb + 31;

    s16x8 qf[2][2];
#pragma unroll
    for (int nt = 0; nt < 2; ++nt)
#pragma unroll
      for (int c = 0; c < 2; ++c)
        qf[nt][c] = *(const s16x8*)(Qp + (qb + nt * 16 + l16) * WW + c * 32 + quad * 8);

    f32x4 O[2][4] = {};
    float m[2], l[2];
    m[0] = m[1] = -__builtin_inff();
    l[0] = l[1] = 0.f;

    const int nkt = qs / 64 + 2;

#pragma unroll
    for (int d = 0; d < 2; ++d) {
      dma16(Kp + (size_t)(srow + d * 8) * WW + scol, &Kbuf[0][(wv * 16 + d * 8) * 64]);
      dma16(Vp + (size_t)(srow + d * 8) * SS + scol, &Vbuf[0][(wv * 16 + d * 8) * 64]);
    }

    for (int kt = 0; kt < nkt; ++kt) {
      const int kb = kt * 64;
      asm volatile("s_waitcnt vmcnt(0)" ::: "memory");
      __syncthreads();
      if (kt + 1 < nkt) {
        const int nb = (kt + 1) & 1;
        const int kbn = kb + 64;
#pragma unroll
        for (int d = 0; d < 2; ++d) {
          dma16(Kp + (size_t)(kbn + srow + d * 8) * WW + scol, &Kbuf[nb][(wv * 16 + d * 8) * 64]);
          dma16(Vp + (size_t)(srow + d * 8) * SS + kbn + scol, &Vbuf[nb][(wv * 16 + d * 8) * 64]);
        }
      }
      if (kb > q_hi) continue;
      const unsigned short* Kb_ = Kbuf[kt & 1];
      const unsigned short* Vb_ = Vbuf[kt & 1];

      s16x8 kf[4][2];
#pragma unroll
      for (int mt = 0; mt < 4; ++mt)
#pragma unroll
        for (int c = 0; c < 2; ++c)
          kf[mt][c] = *(const s16x8*)(Kb_ + (mt * 16 + l16) * 64 + (((c * 4 + quad) ^ (l16 & 7)) << 3));

      f32x4 sc[4][2] = {};
#pragma unroll
      for (int mt = 0; mt < 4; ++mt)
#pragma unroll
        for (int nt = 0; nt < 2; ++nt)
#pragma unroll
          for (int c = 0; c < 2; ++c)
            sc[mt][nt] = __builtin_amdgcn_mfma_f32_16x16x32_bf16(kf[mt][c], qf[nt][c], sc[mt][nt], 0, 0, 0);

      if (kb + 63 > qb) {
#pragma unroll
        for (int mt = 0; mt < 4; ++mt)
#pragma unroll
          for (int nt = 0; nt < 2; ++nt)
#pragma unroll
            for (int r = 0; r < 4; ++r)
              if (kb + mt * 16 + quad * 4 + r > qb + nt * 16 + l16)
                sc[mt][nt][r] = -__builtin_inff();
      }

      float alpha[2];
#pragma unroll
      for (int nt = 0; nt < 2; ++nt) {
        float mx = sc[0][nt][0];
#pragma unroll
        for (int mt = 0; mt < 4; ++mt)
#pragma unroll
          for (int r = 0; r < 4; ++r) mx = fmaxf(mx, sc[mt][nt][r]);
        mx = fmaxf(mx, __shfl_xor(mx, 16));
        mx = fmaxf(mx, __shfl_xor(mx, 32));
        float mn = fmaxf(m[nt], mx);
        alpha[nt] = __builtin_amdgcn_exp2f(m[nt] - mn);
        float s = 0.f;
#pragma unroll
        for (int mt = 0; mt < 4; ++mt)
#pragma unroll
          for (int r = 0; r < 4; ++r) {
            float p = __builtin_amdgcn_exp2f(sc[mt][nt][r] - mn);
            sc[mt][nt][r] = p;
            s += p;
          }
        s += __shfl_xor(s, 16);
        s += __shfl_xor(s, 32);
        l[nt] = l[nt] * alpha[nt] + s;
        m[nt] = mn;
      }

#pragma unroll
      for (int mi = 0; mi < 2; ++mi)
#pragma unroll
        for (int r = 0; r < 4; ++r) {
          float aT = __shfl(alpha[mi], quad * 4 + r);
#pragma unroll
          for (int ni = 0; ni < 4; ++ni) O[mi][ni][r] *= aT;
        }

      asm volatile("s_waitcnt lgkmcnt(0)" ::: "memory");
#pragma unroll
      for (int mt = 0; mt < 4; ++mt)
#pragma unroll
        for (int nt = 0; nt < 2; ++nt) {
          ushort4 pw = make_ushort4(f2bf(sc[mt][nt][0]), f2bf(sc[mt][nt][1]),
                                    f2bf(sc[mt][nt][2]), f2bf(sc[mt][nt][3]));
          *(ushort4*)(Pl + (nt * 16 + l16) * LDP + mt * 16 + quad * 4) = pw;
        }
      asm volatile("s_waitcnt lgkmcnt(0)" ::: "memory");

      s16x8 vf[4][2];
#pragma unroll
      for (int ni = 0; ni < 4; ++ni)
#pragma unroll
        for (int c = 0; c < 2; ++c)
          vf[ni][c] = *(const s16x8*)(Vb_ + (ni * 16 + l16) * 64 + (((c * 4 + quad) ^ (l16 & 7)) << 3));

      s16x8 pf[2][2];
#pragma unroll
      for (int mi = 0; mi < 2; ++mi)
#pragma unroll
        for (int c = 0; c < 2; ++c)
          pf[mi][c] = *(const s16x8*)(Pl + (mi * 16 + l16) * LDP + c * 32 + quad * 8);

#pragma unroll
      for (int mi = 0; mi < 2; ++mi)
#pragma unroll
        for (int ni = 0; ni < 4; ++ni)
#pragma unroll
          for (int c = 0; c < 2; ++c)
            O[mi][ni] = __builtin_amdgcn_mfma_f32_16x16x32_bf16(pf[mi][c], vf[ni][c], O[mi][ni], 0, 0, 0);
    }

#pragma unroll
    for (int mi = 0; mi < 2; ++mi)
#pragma unroll
      for (int r = 0; r < 4; ++r) {
        float linv = 1.f / __shfl(l[mi], quad * 4 + r);
        int q = qb + mi * 16 + quad * 4 + r;
#pragma unroll
        for (int ni = 0; ni < 4; ++ni)
          hm[(size_t)(b * SS + q) * DD + h * WW + ni * 16 + l16] = f2bf(O[mi][ni][r] * linv);
      }
    __syncthreads();
  }
}

extern "C" void kernel_launch(void* const* d_in, const int* in_sizes, int n_in,
                              void* d_out, int out_size, void* d_ws, size_t ws_size,
                              hipStream_t stream) {
  const float* x  = (const float*)d_in[0];
  // d_in[1] = seg : unused by the reference
  const float* Wq = (const float*)d_in[2];
  const float* bq = (const float*)d_in[3];
  const float* Wk = (const float*)d_in[4];
  const float* bk = (const float*)d_in[5];
  const float* Wv = (const float*)d_in[6];
  const float* bv = (const float*)d_in[7];
  const float* Wo = (const float*)d_in[8];
  const float* bo = (const float*)d_in[9];
  float* out = (float*)d_out;

  char* ws = (char*)d_ws;
  unsigned short* xb   = (unsigned short*)(ws);                      // 8 MB
  unsigned short* Wcat = (unsigned short*)(ws + (size_t)( 8 << 20)); // Wtq|Wtk|Wtv, 6 MB contiguous
  unsigned short* Wtq  = Wcat;
  unsigned short* Wtk  = Wcat + (size_t)DD * DD;
  unsigned short* Wtv  = Wcat + (size_t)2 * DD * DD;
  unsigned short* Wto  = (unsigned short*)(ws + (size_t)(14 << 20));
  unsigned short* Qb   = (unsigned short*)(ws + (size_t)(16 << 20)); // 8 MB (B,H,S,W)
  unsigned short* Kb   = (unsigned short*)(ws + (size_t)(24 << 20)); // 8 MB (B,H,S,W)
  unsigned short* Vtb  = (unsigned short*)(ws + (size_t)(32 << 20)); // 8 MB (B,H,W,S)
  unsigned short* hm   = (unsigned short*)(ws + (size_t)(40 << 20)); // 8 MB (B,S,D)

  k_convert_x<<<dim3(MM * DD / 1024), 256, 0, stream>>>(x, xb);

  dim3 tg(32, 32, 4), tb(32, 8);
  k_transpose_w<<<tg, tb, 0, stream>>>(Wq, Wk, Wv, Wo, Wtq, Wtk, Wtv, Wto);

  // fused QKV: 768 blocks = 3 blocks/CU (m97 occupancy regime)
  dim3 gq(24, MM / 128);  // (24, 32)
  k_gemm_qkv<<<gq, 256, 0, stream>>>(xb, Wcat, bq, bk, bv, Qb, Kb, Vtb);

  dim3 ag(SS / 256, BB * HH);  // (8, 32): block p does strips p and 15-p
  k_attn_mfma<<<ag, 256, 0, stream>>>(Qb, Kb, Vtb, hm);

  dim3 go(DD / 64, MM / 64);  // (16, 64) = 1024 blocks = 4/CU
  k_gemm_out<<<go, 256, 0, stream>>>(hm, Wto, bo, out);
}

// Round 10
// 211.418 us; speedup vs baseline: 1.3019x; 1.0431x over previous
//
#include <hip/hip_runtime.h>

#define BB 2
#define SS 2048
#define DD 1024
#define HH 16
#define WW 64
#define MM (BB*SS)  // 4096

typedef float f32x4 __attribute__((ext_vector_type(4)));
typedef short s16x8 __attribute__((ext_vector_type(8)));

__device__ __forceinline__ unsigned short f2bf(float f) {
  return __builtin_bit_cast(unsigned short, (__bf16)f);
}
__device__ __forceinline__ float bf2f(unsigned short u) {
  return (float)__builtin_bit_cast(__bf16, u);
}
// async global->LDS DMA, 16B per lane; lds dst must be wave-uniform (HW adds lane*16)
__device__ __forceinline__ void dma16(const unsigned short* g, unsigned short* l) {
  __builtin_amdgcn_global_load_lds(
      (const __attribute__((address_space(1))) unsigned int*)g,
      (__attribute__((address_space(3))) unsigned int*)l, 16, 0, 0);
}

// ---------------- pre-pass: x fp32 -> bf16 ----------------
__global__ __launch_bounds__(256) void k_convert_x(const float* __restrict__ x,
                                                   unsigned short* __restrict__ xb) {
  int i = (blockIdx.x * 256 + threadIdx.x) * 4;
  float4 v = *(const float4*)(x + i);
  ushort4 o = make_ushort4(f2bf(v.x), f2bf(v.y), f2bf(v.z), f2bf(v.w));
  *(ushort4*)(xb + i) = o;
}

// ---------------- pre-pass: 4x W (KxN fp32) -> Wt (NxK bf16), fused ----------------
__global__ __launch_bounds__(256) void k_transpose_w(const float* __restrict__ W0,
                                                     const float* __restrict__ W1,
                                                     const float* __restrict__ W2,
                                                     const float* __restrict__ W3,
                                                     unsigned short* __restrict__ T0,
                                                     unsigned short* __restrict__ T1,
                                                     unsigned short* __restrict__ T2,
                                                     unsigned short* __restrict__ T3) {
  const float* Wm = blockIdx.z == 0 ? W0 : blockIdx.z == 1 ? W1 : blockIdx.z == 2 ? W2 : W3;
  unsigned short* Wt = blockIdx.z == 0 ? T0 : blockIdx.z == 1 ? T1 : blockIdx.z == 2 ? T2 : T3;
  __shared__ float tile[32][33];
  int bn = blockIdx.x * 32;
  int bk = blockIdx.y * 32;
  int tx = threadIdx.x;
  int ty = threadIdx.y;
#pragma unroll
  for (int r = 0; r < 4; ++r)
    tile[ty + r * 8][tx] = Wm[(bk + ty + r * 8) * DD + bn + tx];
  __syncthreads();
#pragma unroll
  for (int r = 0; r < 4; ++r)
    Wt[(bn + ty + r * 8) * DD + bk + tx] = f2bf(tile[tx][ty + r * 8]);
}

// ---------------- fused QKV GEMM (R8-proven, unchanged) ----------------
__global__ __launch_bounds__(256, 3) void k_gemm_qkv(const unsigned short* __restrict__ A,
                                                     const unsigned short* __restrict__ Wcat,
                                                     const float* __restrict__ bq,
                                                     const float* __restrict__ bk,
                                                     const float* __restrict__ bv,
                                                     unsigned short* __restrict__ Qo,
                                                     unsigned short* __restrict__ Ko,
                                                     unsigned short* __restrict__ Vo) {
  __shared__ __align__(16) unsigned short As[2][128 * 32];
  __shared__ __align__(16) unsigned short Bs[2][128 * 32];
  const int widx = blockIdx.x >> 3;
  const int n0 = (blockIdx.x & 7) * 128;
  const int m0 = blockIdx.y * 128;
  const unsigned short* Bt = Wcat + (size_t)widx * DD * DD;
  const float* bias = widx == 0 ? bq : widx == 1 ? bk : bv;
  unsigned short* outp = widx == 0 ? Qo : widx == 1 ? Ko : Vo;
  const float oscale = widx == 0 ? 0.125f * 1.4426950408889634f : 1.0f;
  const int t = threadIdx.x;
  const int wv = t >> 6, lane = t & 63;
  const int quad = lane >> 4, l16 = lane & 15;
  const int wm = (wv >> 1) * 64, wn = (wv & 1) * 64;
  const unsigned short* srcA[2];
  const unsigned short* srcB[2];
  int dstoff[2];
#pragma unroll
  for (int d = 0; d < 2; ++d) {
    int s = d * 256 + wv * 64 + lane;
    int r = s >> 2, pb = s & 3;
    int lc = ((pb ^ (r & 3)) << 3);
    srcA[d] = A + (size_t)(m0 + r) * DD + lc;
    srcB[d] = Bt + (size_t)(n0 + r) * DD + lc;
    dstoff[d] = (d * 256 + wv * 64) * 8;
  }
  f32x4 acc[4][4] = {};

#pragma unroll
  for (int d = 0; d < 2; ++d) {
    dma16(srcA[d], &As[0][dstoff[d]]);
    dma16(srcB[d], &Bs[0][dstoff[d]]);
  }

  for (int it = 0; it < DD / 32; ++it) {
    asm volatile("s_waitcnt vmcnt(0)" ::: "memory");
    __syncthreads();
    if (it + 1 < DD / 32) {
      const int nb = (it + 1) & 1;
      const int k1 = (it + 1) * 32;
#pragma unroll
      for (int d = 0; d < 2; ++d) {
        dma16(srcA[d] + k1, &As[nb][dstoff[d]]);
        dma16(srcB[d] + k1, &Bs[nb][dstoff[d]]);
      }
    }
    const unsigned short* Asb = As[it & 1];
    const unsigned short* Bsb = Bs[it & 1];
    s16x8 af[4], bfr[4];
#pragma unroll
    for (int mi = 0; mi < 4; ++mi) {
      int ra = wm + mi * 16 + l16;
      af[mi] = *(const s16x8*)(Asb + ra * 32 + ((quad ^ (ra & 3)) << 3));
    }
#pragma unroll
    for (int ni = 0; ni < 4; ++ni) {
      int rb = wn + ni * 16 + l16;
      bfr[ni] = *(const s16x8*)(Bsb + rb * 32 + ((quad ^ (rb & 3)) << 3));
    }
#pragma unroll
    for (int mi = 0; mi < 4; ++mi)
#pragma unroll
      for (int ni = 0; ni < 4; ++ni)
        acc[mi][ni] = __builtin_amdgcn_mfma_f32_16x16x32_bf16(af[mi], bfr[ni], acc[mi][ni], 0, 0, 0);
  }

#pragma unroll
  for (int mi = 0; mi < 4; ++mi) {
#pragma unroll
    for (int ni = 0; ni < 4; ++ni) {
      int col = n0 + wn + ni * 16 + l16;
      float bb = bias[col];
      int h = col >> 6, w = col & 63;
#pragma unroll
      for (int r = 0; r < 4; ++r) {
        int row = m0 + wm + mi * 16 + quad * 4 + r;
        float v = (acc[mi][ni][r] + bb) * oscale;
        int b = row >> 11, s = row & (SS - 1);
        long off;
        if (widx == 2) off = (long)(b * HH + h) * (SS * WW) + (long)w * SS + s;
        else           off = (long)(b * HH + h) * (SS * WW) + (long)s * WW + w;
        outp[off] = f2bf(v);
      }
    }
  }
}

// ---------------- output GEMM: out = hm * Wto^T + bo (fp32) ----------------
// 64x64 tile, BK=32, dma16 double-buffered XOR-swizzled LDS (shrink of the
// proven k_gemm_qkv structure); grid (16,64) = 1024 blocks = 4 blocks/CU.
__global__ __launch_bounds__(256, 4) void k_gemm_out(const unsigned short* __restrict__ A,
                                                     const unsigned short* __restrict__ Bt,
                                                     const float* __restrict__ bias,
                                                     float* __restrict__ out_f) {
  __shared__ __align__(16) unsigned short As[2][64 * 32];
  __shared__ __align__(16) unsigned short Bs[2][64 * 32];
  const int m0 = blockIdx.y * 64, n0 = blockIdx.x * 64;
  const int t = threadIdx.x;
  const int wv = t >> 6, lane = t & 63;
  const int quad = lane >> 4, l16 = lane & 15;
  const int wm = (wv >> 1) * 32, wn = (wv & 1) * 32;
  const int s_ = wv * 64 + lane;
  const int r_ = s_ >> 2, pb_ = s_ & 3;
  const int lc_ = ((pb_ ^ (r_ & 3)) << 3);
  const unsigned short* srcA = A + (size_t)(m0 + r_) * DD + lc_;
  const unsigned short* srcB = Bt + (size_t)(n0 + r_) * DD + lc_;
  const int dstoff = wv * 512;
  f32x4 acc[2][2] = {};

  dma16(srcA, &As[0][dstoff]);
  dma16(srcB, &Bs[0][dstoff]);

  for (int it = 0; it < DD / 32; ++it) {
    asm volatile("s_waitcnt vmcnt(0)" ::: "memory");
    __syncthreads();
    if (it + 1 < DD / 32) {
      const int nb = (it + 1) & 1;
      const int k1 = (it + 1) * 32;
      dma16(srcA + k1, &As[nb][dstoff]);
      dma16(srcB + k1, &Bs[nb][dstoff]);
    }
    const unsigned short* Asb = As[it & 1];
    const unsigned short* Bsb = Bs[it & 1];
    s16x8 af[2], bfr[2];
#pragma unroll
    for (int i = 0; i < 2; ++i) {
      int ra = wm + i * 16 + l16;
      int rb = wn + i * 16 + l16;
      af[i]  = *(const s16x8*)(Asb + ra * 32 + ((quad ^ (ra & 3)) << 3));
      bfr[i] = *(const s16x8*)(Bsb + rb * 32 + ((quad ^ (rb & 3)) << 3));
    }
#pragma unroll
    for (int mi = 0; mi < 2; ++mi)
#pragma unroll
      for (int ni = 0; ni < 2; ++ni)
        acc[mi][ni] = __builtin_amdgcn_mfma_f32_16x16x32_bf16(af[mi], bfr[ni], acc[mi][ni], 0, 0, 0);
  }

#pragma unroll
  for (int mi = 0; mi < 2; ++mi)
#pragma unroll
    for (int ni = 0; ni < 2; ++ni) {
      int col = n0 + wn + ni * 16 + l16;
      float bb = bias[col];
#pragma unroll
      for (int r = 0; r < 4; ++r) {
        int row = m0 + wm + mi * 16 + quad * 4 + r;
        out_f[row * DD + col] = acc[mi][ni][r] + bb;
      }
    }
}

// ---------------- MFMA flash attention: R8 protocol, 128-KEY tiles ----------------
// Block = 256 threads = 4 waves on a 128-query strip; block p processes strips
// p then 15-p (perfect balance: (p+1)+(16-p) = 17 128-key tiles each).
// Cross-wave protocol IDENTICAL to R8 (proven over replays): every wave stages
// a quarter of every K/V tile (4 dma16 per array), pipeline per tile =
// vmcnt(0) -> barrier -> DMA(kt+1) -> compute(kt). Only the within-wave tile
// width changed 64 -> 128 keys: halves barrier count, softmax reductions,
// alpha/rescale passes, and P-roundtrips per unit work; doubles QK MFMA ILP.
// LDS: K 2x16KB + V 2x16KB + P 34KB = 98KB -> 1 block/CU (same as R8).
__global__ __launch_bounds__(256, 1) void k_attn_mfma(const unsigned short* __restrict__ Q,
                                                      const unsigned short* __restrict__ K,
                                                      const unsigned short* __restrict__ Vt,
                                                      unsigned short* __restrict__ hm) {
  constexpr int LDP = 136;  // P row stride (bf16): 272 B, 16B-aligned b128 reads
  __shared__ __align__(16) unsigned short Kbuf[2][128 * 64];  // 32 KB
  __shared__ __align__(16) unsigned short Vbuf[2][64 * 128];  // 32 KB
  __shared__ __align__(16) unsigned short Pl4[4][32 * LDP];   // 34 KB
  const int pairp = blockIdx.x;  // 0..7
  const int bh = blockIdx.y;
  const int t = threadIdx.x;
  const int wv = t >> 6, lane = t & 63;
  const int quad = lane >> 4, l16 = lane & 15;
  unsigned short* Pl = Pl4[wv];
  const unsigned short* Qp = Q + (size_t)bh * SS * WW;
  const unsigned short* Kp = K + (size_t)bh * SS * WW;
  const unsigned short* Vp = Vt + (size_t)bh * WW * SS;
  const int b = bh >> 4, h = bh & 15;

  // K staging: dma D = wv*4+d covers rows D*8 + (lane>>3), 16B-block lane&7.
  // row&7 = lane>>3 (constant across d) -> swizzled col fixed per lane.
  const int rrK = lane >> 3;
  const int kswz = (((lane & 7) ^ rrK) << 3);
  // V staging: dma D = wv*4+d covers rows D*4 + quad, 16B-block lane&15.
  // row&7 = (d*4+quad)&7 varies with d -> swizzle computed per d below.

  for (int sp = 0; sp < 2; ++sp) {
    const int strip = sp == 0 ? pairp : 15 - pairp;
    const int qs = strip * 128;
    const int qb = qs + wv * 32;

    // Q B-fragments: B[n=q_local=l16][k=dim=quad*8+j]
    s16x8 qf[2][2];
#pragma unroll
    for (int nt = 0; nt < 2; ++nt)
#pragma unroll
      for (int c = 0; c < 2; ++c)
        qf[nt][c] = *(const s16x8*)(Qp + (qb + nt * 16 + l16) * WW + c * 32 + quad * 8);

    f32x4 O[2][4] = {};  // C/D: row=q=quad*4+r (+16*mi), col=dim=l16 (+16*ni)
    float m[2], l[2];
    m[0] = m[1] = -__builtin_inff();
    l[0] = l[1] = 0.f;

    const int nkt = qs / 128 + 1;  // 128-key tiles

    // prologue: stage tile 0 into buffer 0 (every wave stages 1/4 of each)
#pragma unroll
    for (int d = 0; d < 4; ++d) {
      const int D = wv * 4 + d;
      dma16(Kp + (size_t)(D * 8 + rrK) * WW + kswz, &Kbuf[0][D * 512]);
      const int vrow = D * 4 + quad;
      dma16(Vp + (size_t)vrow * SS + (((lane & 15) ^ (vrow & 7)) << 3), &Vbuf[0][D * 512]);
    }

    for (int kt = 0; kt < nkt; ++kt) {
      const int kb = kt * 128;
      asm volatile("s_waitcnt vmcnt(0)" ::: "memory");  // this tile's DMA landed
      __syncthreads();                                  // visible to all; prev compute done
      if (kt + 1 < nkt) {                               // prefetch next tile
        const int nb = (kt + 1) & 1;
        const int kbn = kb + 128;
#pragma unroll
        for (int d = 0; d < 4; ++d) {
          const int D = wv * 4 + d;
          dma16(Kp + (size_t)(kbn + D * 8 + rrK) * WW + kswz, &Kbuf[nb][D * 512]);
          const int vrow = D * 4 + quad;
          dma16(Vp + (size_t)vrow * SS + kbn + (((lane & 15) ^ (vrow & 7)) << 3),
                &Vbuf[nb][D * 512]);
        }
      }
      const unsigned short* Kb_ = Kbuf[kt & 1];
      const unsigned short* Vb_ = Vbuf[kt & 1];

      // K A-fragments: row=key_local (8 blocks/row), phys = lb ^ (row&7)
      s16x8 kf[8][2];
#pragma unroll
      for (int mt = 0; mt < 8; ++mt)
#pragma unroll
        for (int c = 0; c < 2; ++c)
          kf[mt][c] = *(const s16x8*)(Kb_ + (mt * 16 + l16) * 64 + (((c * 4 + quad) ^ (l16 & 7)) << 3));

      // S^T: row=key_local=quad*4+r (+16*mt), col=q_local=l16 (+16*nt)
      f32x4 sc[8][2] = {};
#pragma unroll
      for (int mt = 0; mt < 8; ++mt)
#pragma unroll
        for (int nt = 0; nt < 2; ++nt)
#pragma unroll
          for (int c = 0; c < 2; ++c)
            sc[mt][nt] = __builtin_amdgcn_mfma_f32_16x16x32_bf16(kf[mt][c], qf[nt][c], sc[mt][nt], 0, 0, 0);

      if (kt == nkt - 1) {  // diagonal 128-tile: causal mask (all waves)
#pragma unroll
        for (int mt = 0; mt < 8; ++mt)
#pragma unroll
          for (int nt = 0; nt < 2; ++nt)
#pragma unroll
            for (int r = 0; r < 4; ++r)
              if (kb + mt * 16 + quad * 4 + r > qb + nt * 16 + l16)
                sc[mt][nt][r] = -__builtin_inff();
      }

      // online softmax over 128 keys (exp2 domain); stats per q = nt*16+l16
      float alpha[2];
#pragma unroll
      for (int nt = 0; nt < 2; ++nt) {
        float mx = sc[0][nt][0];
#pragma unroll
        for (int mt = 0; mt < 8; ++mt)
#pragma unroll
          for (int r = 0; r < 4; ++r) mx = fmaxf(mx, sc[mt][nt][r]);
        mx = fmaxf(mx, __shfl_xor(mx, 16));
        mx = fmaxf(mx, __shfl_xor(mx, 32));
        float mn = fmaxf(m[nt], mx);
        alpha[nt] = __builtin_amdgcn_exp2f(m[nt] - mn);
        float s = 0.f;
#pragma unroll
        for (int mt = 0; mt < 8; ++mt)
#pragma unroll
          for (int r = 0; r < 4; ++r) {
            float p = __builtin_amdgcn_exp2f(sc[mt][nt][r] - mn);
            sc[mt][nt][r] = p;
            s += p;
          }
        s += __shfl_xor(s, 16);
        s += __shfl_xor(s, 32);
        l[nt] = l[nt] * alpha[nt] + s;
        m[nt] = mn;
      }

      // rescale O: rows q = mi*16 + quad*4 + r -> alpha from lane (quad*4+r)
#pragma unroll
      for (int mi = 0; mi < 2; ++mi)
#pragma unroll
        for (int r = 0; r < 4; ++r) {
          float aT = __shfl(alpha[mi], quad * 4 + r);
#pragma unroll
          for (int ni = 0; ni < 4; ++ni) O[mi][ni][r] *= aT;
        }

      // P -> per-wave LDS region (C/D -> A-operand layout transform)
      asm volatile("s_waitcnt lgkmcnt(0)" ::: "memory");  // WAR on Pl
#pragma unroll
      for (int mt = 0; mt < 8; ++mt)
#pragma unroll
        for (int nt = 0; nt < 2; ++nt) {
          ushort4 pw = make_ushort4(f2bf(sc[mt][nt][0]), f2bf(sc[mt][nt][1]),
                                    f2bf(sc[mt][nt][2]), f2bf(sc[mt][nt][3]));
          *(ushort4*)(Pl + (nt * 16 + l16) * LDP + mt * 16 + quad * 4) = pw;
        }
      asm volatile("s_waitcnt lgkmcnt(0)" ::: "memory");  // RAW on Pl

      // V^T B-fragments (kf dead): row=dim (16 blocks/row), phys = lb^(row&7)
      s16x8 vf[4][4];
#pragma unroll
      for (int ni = 0; ni < 4; ++ni)
#pragma unroll
        for (int c = 0; c < 4; ++c)
          vf[ni][c] = *(const s16x8*)(Vb_ + (ni * 16 + l16) * 128 + (((c * 4 + quad) ^ (l16 & 7)) << 3));

      // P A-fragments: A[m=q_local=l16][k=key=c*32+quad*8+j]
      s16x8 pf[2][4];
#pragma unroll
      for (int mi = 0; mi < 2; ++mi)
#pragma unroll
        for (int c = 0; c < 4; ++c)
          pf[mi][c] = *(const s16x8*)(Pl + (mi * 16 + l16) * LDP + c * 32 + quad * 8);

      // O += P * V^T over 128 keys
#pragma unroll
      for (int mi = 0; mi < 2; ++mi)
#pragma unroll
        for (int ni = 0; ni < 4; ++ni)
#pragma unroll
          for (int c = 0; c < 4; ++c)
            O[mi][ni] = __builtin_amdgcn_mfma_f32_16x16x32_bf16(pf[mi][c], vf[ni][c], O[mi][ni], 0, 0, 0);
    }

    // epilogue: divide by l, write head-merged (B,S,D)
#pragma unroll
    for (int mi = 0; mi < 2; ++mi)
#pragma unroll
      for (int r = 0; r < 4; ++r) {
        float linv = 1.f / __shfl(l[mi], quad * 4 + r);
        int q = qb + mi * 16 + quad * 4 + r;
#pragma unroll
        for (int ni = 0; ni < 4; ++ni)
          hm[(size_t)(b * SS + q) * DD + h * WW + ni * 16 + l16] = f2bf(O[mi][ni][r] * linv);
      }
    __syncthreads();  // all waves done with Kbuf/Vbuf before next strip's prologue
  }
}

extern "C" void kernel_launch(void* const* d_in, const int* in_sizes, int n_in,
                              void* d_out, int out_size, void* d_ws, size_t ws_size,
                              hipStream_t stream) {
  const float* x  = (const float*)d_in[0];
  // d_in[1] = seg : unused by the reference
  const float* Wq = (const float*)d_in[2];
  const float* bq = (const float*)d_in[3];
  const float* Wk = (const float*)d_in[4];
  const float* bk = (const float*)d_in[5];
  const float* Wv = (const float*)d_in[6];
  const float* bv = (const float*)d_in[7];
  const float* Wo = (const float*)d_in[8];
  const float* bo = (const float*)d_in[9];
  float* out = (float*)d_out;

  char* ws = (char*)d_ws;
  unsigned short* xb   = (unsigned short*)(ws);                      // 8 MB
  unsigned short* Wcat = (unsigned short*)(ws + (size_t)( 8 << 20)); // Wtq|Wtk|Wtv
  unsigned short* Wtq  = Wcat;
  unsigned short* Wtk  = Wcat + (size_t)DD * DD;
  unsigned short* Wtv  = Wcat + (size_t)2 * DD * DD;
  unsigned short* Wto  = (unsigned short*)(ws + (size_t)(14 << 20));
  unsigned short* Qb   = (unsigned short*)(ws + (size_t)(16 << 20)); // 8 MB (B,H,S,W)
  unsigned short* Kb   = (unsigned short*)(ws + (size_t)(24 << 20)); // 8 MB (B,H,S,W)
  unsigned short* Vtb  = (unsigned short*)(ws + (size_t)(32 << 20)); // 8 MB (B,H,W,S)
  unsigned short* hm   = (unsigned short*)(ws + (size_t)(40 << 20)); // 8 MB (B,S,D)

  k_convert_x<<<dim3(MM * DD / 1024), 256, 0, stream>>>(x, xb);

  dim3 tg(32, 32, 4), tb(32, 8);
  k_transpose_w<<<tg, tb, 0, stream>>>(Wq, Wk, Wv, Wo, Wtq, Wtk, Wtv, Wto);

  dim3 gq(24, MM / 128);  // (24, 32) = 768 blocks = 3/CU
  k_gemm_qkv<<<gq, 256, 0, stream>>>(xb, Wcat, bq, bk, bv, Qb, Kb, Vtb);

  dim3 ag(SS / 256, BB * HH);  // (8, 32): block p does strips p and 15-p
  k_attn_mfma<<<ag, 256, 0, stream>>>(Qb, Kb, Vtb, hm);

  dim3 go(DD / 64, MM / 64);  // (16, 64) = 1024 blocks = 4/CU
  k_gemm_out<<<go, 256, 0, stream>>>(hm, Wto, bo, out);
}